// Round 4
// baseline (295.430 us; speedup 1.0000x reference)
//
#include <hip/hip_runtime.h>

#define NB 48
#define NT 5000
#define NF 161
#define NROWS (NB * NT)               // 240000
#define MAGN  ((size_t)NROWS * NF)    // 38640000

typedef float vf4 __attribute__((ext_vector_type(4)));

// Kernel A: per-row weighted power + sqrt — direct-read, no LDS.
// One row (161 floats = 644 B) per wave per iteration: lanes 0..39 load one
// float4 each (640 B dense contiguous), lane 40 loads the Nyquist bin scalar
// (no OOB read past the buffer).  3 FMAs + 6 shfl_down per row, lane 0 writes
// sqrt(sum/320).  No LDS staging (data has zero reuse), no __syncthreads, DS
// pipe use drops from ~9.4 to 6 ops/row -> pure HBM stream.
// 2048 blocks x 4 waves = 8192 waves, ~29 rows each (grid-stride).
__global__ __launch_bounds__(256) void x_kernel(const float* __restrict__ mag,
                                                float* __restrict__ gout) {
    const int tid  = threadIdx.x;
    const int lane = tid & 63;
    const int gw   = blockIdx.x * 4 + (tid >> 6);   // global wave id
    const int nw   = gridDim.x * 4;                 // total waves

#pragma unroll 2
    for (int row = gw; row < NROWS; row += nw) {
        const float* rp = mag + (size_t)row * NF;
        float4 v = make_float4(0.f, 0.f, 0.f, 0.f);
        if (lane < 40)       v = ((const float4*)rp)[lane];
        else if (lane == 40) v.x = rp[160];

        const float d = v.x * v.x + v.y * v.y + v.z * v.z + v.w * v.w;
        float s = 2.f * d;                 // interior bins counted twice
        if (lane == 0)  s = 2.f * d - v.x * v.x;   // DC counted once
        if (lane == 40) s = d;                     // Nyquist counted once
        // lanes 41..63: v == 0 -> s == 0

#pragma unroll
        for (int off = 32; off > 0; off >>= 1)
            s += __shfl_down(s, off, 64);
        if (lane == 0)
            gout[row] = sqrtf(s / 320.f);
    }
}

// Kernel B: in-place EMA scan over T per batch.  One block per batch.
// Affine-composite parallel scan: segment == map g -> A*g + B.
__global__ __launch_bounds__(256) void scan_kernel(float* __restrict__ gbuf) {
    __shared__ __align__(16) float sx[NT];        // 20000 B
    __shared__ float sA[256];
    __shared__ float sB[256];
    const int b   = blockIdx.x;
    const int tid = threadIdx.x;
    float* gp = gbuf + (size_t)b * NT;

    // float4 staging load (NT = 5000 = 1250 float4; gbuf 16B-aligned)
    {
        const float4* gp4 = (const float4*)gp;
        float4* sp4 = (float4*)sx;
        for (int i4 = tid; i4 < NT / 4; i4 += 256) sp4[i4] = gp4[i4];
    }
    __syncthreads();

    const int LEN   = 20;                         // ceil((NT-1)/256)
    const int start = 1 + tid * LEN;
    const int end   = min(NT, start + LEN);

    float A = 1.f, Bc = 0.f;
    for (int t = start; t < end; ++t) {
        A  *= 0.9f;
        Bc  = 0.9f * Bc + 0.1f * sx[t];
    }
    sA[tid] = A; sB[tid] = Bc;
    __syncthreads();

    // Hillis-Steele inclusive scan of affine maps
    for (int off = 1; off < 256; off <<= 1) {
        float a = sA[tid], bb = sB[tid];
        float ap = 1.f, bp = 0.f;
        if (tid >= off) { ap = sA[tid - off]; bp = sB[tid - off]; }
        __syncthreads();
        sA[tid] = a * ap;
        sB[tid] = a * bp + bb;
        __syncthreads();
    }

    // exclusive prefix of this thread = inclusive of tid-1; seed g[0] = x[0]
    float Ap = 1.f, Bp = 0.f;
    if (tid > 0) { Ap = sA[tid - 1]; Bp = sB[tid - 1]; }
    float g = Ap * sx[0] + Bp;                    // g at t = start-1

    if (tid == 0) gp[0] = sx[0];
    for (int t = start; t < end; ++t) {
        g = 0.9f * g + 0.1f * sx[t];
        gp[t] = g;
    }
}

// Kernel C: new_mag = mag * rcp(gain[row] + 0.001), float4, grid-stride.
// NT load (mag re-read is dead after use; hits LLC per R2 traffic audit) and
// NT store (out never re-read).  2048 blocks x 256 thr; ~18 float4/thread.
__global__ __launch_bounds__(256) void div_kernel(const float* __restrict__ mag,
                                                  const float* __restrict__ gain,
                                                  float* __restrict__ out) {
    const unsigned n4 = (unsigned)(MAGN / 4);     // 9660000
    const unsigned stride = 2048u * 256u;
    const vf4* mag4 = (const vf4*)mag;
    vf4* out4 = (vf4*)out;

    for (unsigned i4 = blockIdx.x * 256u + threadIdx.x; i4 < n4; i4 += stride) {
        vf4 m = __builtin_nontemporal_load(&mag4[i4]);
        const unsigned base = i4 * 4u;
        const unsigned row0 = base / NF;          // magic-mul div by 161
        const unsigned row3 = (base + 3u) / NF;   // at most one row boundary in 4 elems
        const float ga = __builtin_amdgcn_rcpf(gain[row0] + 0.001f);
        const float gb = __builtin_amdgcn_rcpf(gain[row3] + 0.001f);
        const unsigned lim = (row0 + 1u) * NF;    // first index of next row

        vf4 o;
        o.x = m.x * ga;
        o.y = m.y * ((base + 1u < lim) ? ga : gb);
        o.z = m.z * ((base + 2u < lim) ? ga : gb);
        o.w = m.w * gb;
        __builtin_nontemporal_store(o, &out4[i4]);
    }
}

extern "C" void kernel_launch(void* const* d_in, const int* in_sizes, int n_in,
                              void* d_out, int out_size, void* d_ws, size_t ws_size,
                              hipStream_t stream) {
    const float* mag = (const float*)d_in[0];
    float* out  = (float*)d_out;
    float* gout = out + (size_t)MAGN;             // slice_gain region [B*T]

    x_kernel<<<2048, 256, 0, stream>>>(mag, gout);
    scan_kernel<<<NB, 256, 0, stream>>>(gout);
    div_kernel<<<2048, 256, 0, stream>>>(mag, gout, out);
}